// Round 10
// baseline (173.652 us; speedup 1.0000x reference)
//
#include <hip/hip_runtime.h>
#include <hip/hip_cooperative_groups.h>

namespace cg = cooperative_groups;

#define B_   512
#define F_   2048
#define K_   64
#define D_   16
#define N_   1024
#define OUTW (F_+K_)    // 2112
#define LOG2E 1.44269504088896340736f

typedef __attribute__((ext_vector_type(8))) short short8;
typedef __attribute__((ext_vector_type(4))) float f32x4;

__device__ __forceinline__ ushort f2bf(float f) {
    union { float f; unsigned u; } un; un.f = f;
    unsigned u = un.u;
    u += 0x7FFF + ((u >> 16) & 1);   // RNE
    return (ushort)(u >> 16);
}

// exp2 via raw v_exp_f32, negation folded into the input modifier (verified r9)
__device__ __forceinline__ float exp2_neg(float x) {
    float r;
    asm("v_exp_f32 %0, -%1" : "=v"(r) : "v"(x));
    return r;
}

// One cooperative kernel, 256 blocks x 512 threads (1 block/CU co-resident).
// Phase A: out[:, :2048] = x; xb = bf16(x*log2e); wt[n][f] = bf16(W[f][n])
// Phase B: GEMM act[k][b][d] via MFMA, 8 waves = 4 quadrants x 2 K-halves + LDS reduce
// Phase C: pairwise exp-sum feats -> out[:, 2048:]
__global__ __launch_bounds__(512) void fused_kernel(const float* __restrict__ x,
                                                    const float* __restrict__ w,
                                                    float* __restrict__ out,
                                                    ushort* __restrict__ xb,
                                                    ushort* __restrict__ wt,
                                                    float* __restrict__ act) {
    __shared__ float lds[8192 + 512];    // 34 KB, reused across phases
    const int tid = threadIdx.x;
    const int blk = blockIdx.x;
    cg::grid_group grid = cg::this_grid();

    // ---------------- Phase A1: x convert + out copy ----------------
    {
        const int base = blk * 512 + tid;             // 131072 threads
        #pragma unroll
        for (int i = 0; i < 2; ++i) {
            const int idx = base + i * 131072;        // float4 idx 0..262143
            float4 v = ((const float4*)x)[idx];
            const int b = idx >> 9, c = idx & 511;
            ((float4*)out)[b * (OUTW / 4) + c] = v;
            ushort4 u = make_ushort4(f2bf(v.x * LOG2E), f2bf(v.y * LOG2E),
                                     f2bf(v.z * LOG2E), f2bf(v.w * LOG2E));
            ((ushort4*)xb)[idx] = u;
        }
    }
    // ---------------- Phase A2: W transpose-convert (8 32x32 tiles/block) ----------------
    {
        float (*t)[33] = (float(*)[33])lds;
        const int r  = tid >> 4;           // 0..31
        const int c2 = (tid & 15) * 2;     // 0..30
        float2 vv[8];
        #pragma unroll
        for (int i = 0; i < 8; ++i) {
            const int tile = blk * 8 + i;  // 0..2047
            vv[i] = *(const float2*)(w + (size_t)((tile >> 5) * 32 + r) * N_ + (tile & 31) * 32 + c2);
        }
        #pragma unroll
        for (int i = 0; i < 8; ++i) {
            const int tile = blk * 8 + i;
            const int f0 = (tile >> 5) * 32, n0 = (tile & 31) * 32;
            __syncthreads();               // prev iter's readers done
            t[r][c2] = vv[i].x; t[r][c2 + 1] = vv[i].y;
            __syncthreads();
            ushort2 u = make_ushort2(f2bf(t[c2][r]), f2bf(t[c2 + 1][r]));
            *(ushort2*)(wt + (size_t)(n0 + r) * F_ + f0 + c2) = u;
        }
    }
    grid.sync();

    // ---------------- Phase B: MFMA GEMM, 64x32 tile, 2-way in-block split-K ----------------
    {
        const int l  = tid & 63;
        const int wv = tid >> 6;                 // 0..7
        const int bm0 = (blk >> 5) * 64;         // 8 m-tiles
        const int bn0 = (blk & 31) * 32;         // 32 n-tiles
        const int mw = ((wv >> 1) & 1) * 32;     // quadrant (same for wv and wv+4)
        const int nw = (wv & 1) * 16;
        const int khalf = (wv >> 2) * 1024;      // 0 or 1024
        const int lr = l & 15;
        const int lk = (l >> 4) * 8;

        const ushort* pa0 = xb + (size_t)(bm0 + mw + lr) * F_ + khalf + lk;
        const ushort* pa1 = pa0 + 16 * F_;
        const ushort* pb0 = wt + (size_t)(bn0 + nw + lr) * F_ + khalf + lk;

        f32x4 acc0 = {}, acc1 = {};
        #pragma unroll 4
        for (int kk = 0; kk < 1024; kk += 32) {
            short8 a0 = *(const short8*)(pa0 + kk);
            short8 a1 = *(const short8*)(pa1 + kk);
            short8 b0 = *(const short8*)(pb0 + kk);
            acc0 = __builtin_amdgcn_mfma_f32_16x16x32_bf16(a0, b0, acc0, 0, 0, 0);
            acc1 = __builtin_amdgcn_mfma_f32_16x16x32_bf16(a1, b0, acc1, 0, 0, 0);
        }

        // cross-wave K reduction: slot layout [quad][j][lane] (conflict-free stride-1)
        if (wv >= 4) {
            #pragma unroll
            for (int j = 0; j < 4; ++j) {
                lds[(((wv - 4) * 8 + j) * 64) + l]     = acc0[j];
                lds[(((wv - 4) * 8 + j + 4) * 64) + l] = acc1[j];
            }
        }
        __syncthreads();
        if (wv < 4) {
            #pragma unroll
            for (int j = 0; j < 4; ++j) {
                acc0[j] += lds[((wv * 8 + j) * 64) + l];
                acc1[j] += lds[((wv * 8 + j + 4) * 64) + l];
            }
            // D layout: col = l&15 (n), row = (l>>4)*4 + reg (m)
            const int n = bn0 + nw + lr;
            const int k = n >> 4, d = n & 15;
            const int mbase = bm0 + mw + (l >> 4) * 4;
            float* dst = act + (size_t)k * (B_ * D_) + d;
            #pragma unroll
            for (int r = 0; r < 4; ++r) {
                dst[(size_t)(mbase + r) * D_]      = acc0[r];
                dst[(size_t)(mbase + 16 + r) * D_] = acc1[r];
            }
        }
    }
    grid.sync();

    // ---------------- Phase C: pairwise exp-sum (2 (bt,k) units/block) ----------------
    {
        const int lane = tid & 63;
        const int wv   = tid >> 6;           // 0..7, each wave does 64 b2
        float* s_act = lds;                  // 8192 floats
        float* red   = lds + 8192;           // 512 floats
        #pragma unroll 1
        for (int half = 0; half < 2; ++half) {
            const int u  = blk + half * 256;
            const int bt = u & 7, k = u >> 3;
            __syncthreads();                 // prev half's s_act/red readers done
            const float4* src = (const float4*)(act + (size_t)k * (B_ * D_));
            #pragma unroll
            for (int i = 0; i < 4; ++i)
                ((float4*)s_act)[tid + i * 512] = src[tid + i * 512];
            __syncthreads();

            const int b = bt * 64 + lane;
            const float4* arow = (const float4*)&s_act[b * D_];
            const float4 a0 = arow[0], a1 = arow[1], a2 = arow[2], a3 = arow[3];

            float p0 = 0.0f, p1 = 0.0f;
            const int b2lo = wv * 64;
            #pragma unroll 2
            for (int b2 = b2lo; b2 < b2lo + 64; b2 += 2) {
                {
                    const float4* v = (const float4*)&s_act[b2 * D_];
                    const float4 v0 = v[0], v1 = v[1], v2 = v[2], v3 = v[3];
                    float t0 = fabsf(a0.x - v0.x) + fabsf(a0.y - v0.y);
                    float t1 = fabsf(a0.z - v0.z) + fabsf(a0.w - v0.w);
                    float t2 = fabsf(a1.x - v1.x) + fabsf(a1.y - v1.y);
                    float t3 = fabsf(a1.z - v1.z) + fabsf(a1.w - v1.w);
                    float t4 = fabsf(a2.x - v2.x) + fabsf(a2.y - v2.y);
                    float t5 = fabsf(a2.z - v2.z) + fabsf(a2.w - v2.w);
                    float t6 = fabsf(a3.x - v3.x) + fabsf(a3.y - v3.y);
                    float t7 = fabsf(a3.z - v3.z) + fabsf(a3.w - v3.w);
                    float s = ((t0 + t1) + (t2 + t3)) + ((t4 + t5) + (t6 + t7));
                    p0 += exp2_neg(s);
                }
                {
                    const float4* v = (const float4*)&s_act[(b2 + 1) * D_];
                    const float4 v0 = v[0], v1 = v[1], v2 = v[2], v3 = v[3];
                    float t0 = fabsf(a0.x - v0.x) + fabsf(a0.y - v0.y);
                    float t1 = fabsf(a0.z - v0.z) + fabsf(a0.w - v0.w);
                    float t2 = fabsf(a1.x - v1.x) + fabsf(a1.y - v1.y);
                    float t3 = fabsf(a1.z - v1.z) + fabsf(a1.w - v1.w);
                    float t4 = fabsf(a2.x - v2.x) + fabsf(a2.y - v2.y);
                    float t5 = fabsf(a2.z - v2.z) + fabsf(a2.w - v2.w);
                    float t6 = fabsf(a3.x - v3.x) + fabsf(a3.y - v3.y);
                    float t7 = fabsf(a3.z - v3.z) + fabsf(a3.w - v3.w);
                    float s = ((t0 + t1) + (t2 + t3)) + ((t4 + t5) + (t6 + t7));
                    p1 += exp2_neg(s);
                }
            }

            red[wv * 64 + lane] = p0 + p1;
            __syncthreads();
            if (wv == 0) {
                float total = 0.0f;
                #pragma unroll
                for (int i = 0; i < 8; ++i) total += red[i * 64 + lane];
                out[(size_t)b * OUTW + F_ + k] = total;
            }
        }
    }
}

extern "C" void kernel_launch(void* const* d_in, const int* in_sizes, int n_in,
                              void* d_out, int out_size, void* d_ws, size_t ws_size,
                              hipStream_t stream) {
    const float* x = (const float*)d_in[0];
    const float* wsrc = (const float*)d_in[1];
    float* out = (float*)d_out;

    // ws: xb bf16 [512][2048] (2MB) | wt bf16 [1024][2048] (4MB) | act f32 [64][512][16] (2MB)
    ushort* xb  = (ushort*)d_ws;
    ushort* wt  = (ushort*)((char*)d_ws + (size_t)2 * 1024 * 1024);
    float*  act = (float*)((char*)d_ws + (size_t)6 * 1024 * 1024);

    void* args[] = {(void*)&x, (void*)&wsrc, (void*)&out, (void*)&xb, (void*)&wt, (void*)&act};
    hipLaunchCooperativeKernel((const void*)fused_kernel, dim3(256), dim3(512), args, 0, stream);
}

// Round 12
// 120.623 us; speedup vs baseline: 1.4396x; 1.4396x over previous
//
#include <hip/hip_runtime.h>

#define B_   512
#define F_   2048
#define K_   64
#define D_   16
#define N_   1024
#define OUTW (F_+K_)    // 2112
#define LOG2E 1.44269504088896340736f

typedef __attribute__((ext_vector_type(8))) short short8;
typedef __attribute__((ext_vector_type(4))) float f32x4;

__device__ __forceinline__ ushort f2bf(float f) {
    union { float f; unsigned u; } un; un.f = f;
    unsigned u = un.u;
    u += 0x7FFF + ((u >> 16) & 1);   // RNE
    return (ushort)(u >> 16);
}

// exp2 via raw v_exp_f32, negation folded into the input modifier
__device__ __forceinline__ float exp2_neg(float x) {
    float r;
    asm("v_exp_f32 %0, -%1" : "=v"(r) : "v"(x));
    return r;
}

// ---- prep: blocks 0..1023: out[:, :2048]=x, xb=bf16(x*log2e)
//            blocks 1024..1279: wt[n][f]=bf16(W[f][n]) (8 32x32 tiles each) ----
__global__ __launch_bounds__(256) void prep_kernel(const float* __restrict__ x,
                                                   const float* __restrict__ w,
                                                   float* __restrict__ out,
                                                   ushort* __restrict__ xb,
                                                   ushort* __restrict__ wt) {
    __shared__ float t[32][33];
    const int blk = blockIdx.x;
    const int tid = threadIdx.x;
    if (blk < 1024) {
        const int i = blk * 256 + tid;                // 262144 float4's
        float4 v = ((const float4*)x)[i];
        const int b = i >> 9, c = i & 511;
        ((float4*)out)[b * (OUTW / 4) + c] = v;
        ushort4 u = make_ushort4(f2bf(v.x * LOG2E), f2bf(v.y * LOG2E),
                                 f2bf(v.z * LOG2E), f2bf(v.w * LOG2E));
        ((ushort4*)xb)[i] = u;
    } else {
        const int r  = tid >> 3;           // 0..31
        const int c4 = (tid & 7) * 4;      // 0..28
        #pragma unroll 1
        for (int i = 0; i < 8; ++i) {
            const int tb = (blk - 1024) * 8 + i;     // 0..2047
            const int f0 = (tb >> 5) * 32, n0 = (tb & 31) * 32;
            float4 v = *(const float4*)(w + (size_t)(f0 + r) * N_ + n0 + c4);
            __syncthreads();               // prev iter's readers done
            t[r][c4 + 0] = v.x; t[r][c4 + 1] = v.y;
            t[r][c4 + 2] = v.z; t[r][c4 + 3] = v.w;
            __syncthreads();
            ushort4 u = make_ushort4(f2bf(t[c4 + 0][r]), f2bf(t[c4 + 1][r]),
                                     f2bf(t[c4 + 2][r]), f2bf(t[c4 + 3][r]));
            *(ushort4*)(wt + (size_t)(n0 + r) * F_ + f0 + c4) = u;
        }
    }
}

// ---- MFMA GEMM, split-K=4 into 4 partial buffers (no atomics, no memset) ----
// grid (8 m, 32 n, 4 ksplit) = 1024 blocks (4/CU, 4 waves/SIMD), 64x32 tile, 4 waves.
__global__ __launch_bounds__(256) void gemm_mfma_kernel(const ushort* __restrict__ xb,
                                                        const ushort* __restrict__ wt,
                                                        float* __restrict__ actp) {
    const int bm0 = blockIdx.x * 64;
    const int bn0 = blockIdx.y * 32;
    const int f0  = blockIdx.z * 512;
    const int tid = threadIdx.x;
    const int l   = tid & 63;
    const int w   = tid >> 6;
    const int mw  = (w >> 1) * 32;     // 0,32
    const int nw  = (w & 1) * 16;      // 0,16
    const int lr  = l & 15;
    const int lk  = (l >> 4) * 8;

    const ushort* pa0 = xb + (size_t)(bm0 + mw + lr) * F_ + f0 + lk;
    const ushort* pa1 = pa0 + 16 * F_;
    const ushort* pb0 = wt + (size_t)(bn0 + nw + lr) * F_ + f0 + lk;

    f32x4 acc0 = {}, acc1 = {};
    #pragma unroll 4
    for (int kk = 0; kk < 512; kk += 32) {
        short8 a0 = *(const short8*)(pa0 + kk);
        short8 a1 = *(const short8*)(pa1 + kk);
        short8 b0 = *(const short8*)(pb0 + kk);
        acc0 = __builtin_amdgcn_mfma_f32_16x16x32_bf16(a0, b0, acc0, 0, 0, 0);
        acc1 = __builtin_amdgcn_mfma_f32_16x16x32_bf16(a1, b0, acc1, 0, 0, 0);
    }

    // D layout: col = l&15 (n), row = (l>>4)*4 + reg (m)
    const int n = bn0 + nw + lr;
    const int k = n >> 4, d = n & 15;
    const int mbase = bm0 + mw + (l >> 4) * 4;
    float* dst = actp + (size_t)blockIdx.z * (K_ * B_ * D_) + (size_t)k * (B_ * D_) + d;
    #pragma unroll
    for (int r = 0; r < 4; ++r) {
        dst[(size_t)(mbase + r) * D_]      = acc0[r];
        dst[(size_t)(mbase + 16 + r) * D_] = acc1[r];
    }
}

// ---- pairwise: stage sums 4 partials, then exp2-sum. 512 thr, 8 waves x 64 b2 ----
__global__ __launch_bounds__(512) void pairwise_kernel(const float* __restrict__ actp,
                                                       float* __restrict__ out) {
    __shared__ float s_act[B_ * D_];   // 32 KB
    __shared__ float red[8][64];

    const int bt = blockIdx.x;    // 8
    const int k  = blockIdx.y;    // 64
    const int tid  = threadIdx.x;
    const int lane = tid & 63;
    const int wave = tid >> 6;

    const f32x4* p0 = (const f32x4*)(actp + (size_t)k * (B_ * D_));
    const f32x4* p1 = p0 + (K_ * B_ * D_) / 4;
    const f32x4* p2 = p1 + (K_ * B_ * D_) / 4;
    const f32x4* p3 = p2 + (K_ * B_ * D_) / 4;
    #pragma unroll
    for (int i = 0; i < 4; ++i) {
        const int idx = tid + i * 512;
        ((f32x4*)s_act)[idx] = (p0[idx] + p1[idx]) + (p2[idx] + p3[idx]);
    }
    __syncthreads();

    const int b = bt * 64 + lane;
    const float4* arow = (const float4*)&s_act[b * D_];
    const float4 a0 = arow[0], a1 = arow[1], a2 = arow[2], a3 = arow[3];

    float p0a = 0.0f, p1a = 0.0f;
    const int b2lo = wave * 64;
    #pragma unroll 2
    for (int b2 = b2lo; b2 < b2lo + 64; b2 += 2) {
        {
            const float4* v = (const float4*)&s_act[b2 * D_];
            const float4 v0 = v[0], v1 = v[1], v2 = v[2], v3 = v[3];
            float t0 = fabsf(a0.x - v0.x) + fabsf(a0.y - v0.y);
            float t1 = fabsf(a0.z - v0.z) + fabsf(a0.w - v0.w);
            float t2 = fabsf(a1.x - v1.x) + fabsf(a1.y - v1.y);
            float t3 = fabsf(a1.z - v1.z) + fabsf(a1.w - v1.w);
            float t4 = fabsf(a2.x - v2.x) + fabsf(a2.y - v2.y);
            float t5 = fabsf(a2.z - v2.z) + fabsf(a2.w - v2.w);
            float t6 = fabsf(a3.x - v3.x) + fabsf(a3.y - v3.y);
            float t7 = fabsf(a3.z - v3.z) + fabsf(a3.w - v3.w);
            float s = ((t0 + t1) + (t2 + t3)) + ((t4 + t5) + (t6 + t7));
            p0a += exp2_neg(s);
        }
        {
            const float4* v = (const float4*)&s_act[(b2 + 1) * D_];
            const float4 v0 = v[0], v1 = v[1], v2 = v[2], v3 = v[3];
            float t0 = fabsf(a0.x - v0.x) + fabsf(a0.y - v0.y);
            float t1 = fabsf(a0.z - v0.z) + fabsf(a0.w - v0.w);
            float t2 = fabsf(a1.x - v1.x) + fabsf(a1.y - v1.y);
            float t3 = fabsf(a1.z - v1.z) + fabsf(a1.w - v1.w);
            float t4 = fabsf(a2.x - v2.x) + fabsf(a2.y - v2.y);
            float t5 = fabsf(a2.z - v2.z) + fabsf(a2.w - v2.w);
            float t6 = fabsf(a3.x - v3.x) + fabsf(a3.y - v3.y);
            float t7 = fabsf(a3.z - v3.z) + fabsf(a3.w - v3.w);
            float s = ((t0 + t1) + (t2 + t3)) + ((t4 + t5) + (t6 + t7));
            p1a += exp2_neg(s);
        }
    }

    red[wave][lane] = p0a + p1a;
    __syncthreads();
    if (wave == 0) {
        float total = 0.0f;
        #pragma unroll
        for (int i = 0; i < 8; ++i) total += red[i][lane];
        out[(size_t)b * OUTW + F_ + k] = total;
    }
}

extern "C" void kernel_launch(void* const* d_in, const int* in_sizes, int n_in,
                              void* d_out, int out_size, void* d_ws, size_t ws_size,
                              hipStream_t stream) {
    const float* x = (const float*)d_in[0];
    const float* wsrc = (const float*)d_in[1];
    float* out = (float*)d_out;

    // ws: xb bf16 [512][2048] (2MB) | wt bf16 [1024][2048] (4MB) | actp f32 [4][64][512][16] (8MB)
    ushort* xb   = (ushort*)d_ws;
    ushort* wt   = (ushort*)((char*)d_ws + (size_t)2 * 1024 * 1024);
    float*  actp = (float*)((char*)d_ws + (size_t)6 * 1024 * 1024);

    prep_kernel<<<1280, 256, 0, stream>>>(x, wsrc, out, xb, wt);
    gemm_mfma_kernel<<<dim3(8, 32, 4), 256, 0, stream>>>(xb, wt, actp);
    pairwise_kernel<<<dim3(8, K_), 512, 0, stream>>>(actp, out);
}

// Round 13
// 103.173 us; speedup vs baseline: 1.6831x; 1.1691x over previous
//
#include <hip/hip_runtime.h>
#include <hip/hip_fp16.h>

#define B_   512
#define F_   2048
#define K_   64
#define D_   16
#define N_   1024
#define OUTW (F_+K_)    // 2112
#define LOG2E 1.44269504088896340736f
#define KSPLIT 4
#define KCH  (F_/KSPLIT)   // 512
#define BK   64
#define NSTEP (KCH/BK)     // 8

typedef __attribute__((ext_vector_type(8))) short short8;
typedef __attribute__((ext_vector_type(4))) float f32x4;

__device__ __forceinline__ ushort f2bf(float f) {
    union { float f; unsigned u; } un; un.f = f;
    unsigned u = un.u;
    u += 0x7FFF + ((u >> 16) & 1);   // RNE
    return (ushort)(u >> 16);
}

// exp2 via raw v_exp_f32, negation folded into the input modifier
__device__ __forceinline__ float exp2_neg(float x) {
    float r;
    asm("v_exp_f32 %0, -%1" : "=v"(r) : "v"(x));
    return r;
}

// ---- prep: blocks 0..1023: out[:, :2048]=x, xb=bf16(x*log2e)
//            blocks 1024..1279: wt[n][f]=bf16(W[f][n]) ----
__global__ __launch_bounds__(256) void prep_kernel(const float* __restrict__ x,
                                                   const float* __restrict__ w,
                                                   float* __restrict__ out,
                                                   ushort* __restrict__ xb,
                                                   ushort* __restrict__ wt) {
    __shared__ float t[32][33];
    const int blk = blockIdx.x;
    const int tid = threadIdx.x;
    if (blk < 1024) {
        const int i = blk * 256 + tid;                // 262144 float4's
        float4 v = ((const float4*)x)[i];
        const int b = i >> 9, c = i & 511;
        ((float4*)out)[b * (OUTW / 4) + c] = v;
        ushort4 u = make_ushort4(f2bf(v.x * LOG2E), f2bf(v.y * LOG2E),
                                 f2bf(v.z * LOG2E), f2bf(v.w * LOG2E));
        ((ushort4*)xb)[i] = u;
    } else {
        const int r  = tid >> 3;           // 0..31
        const int c4 = (tid & 7) * 4;      // 0..28
        #pragma unroll 1
        for (int i = 0; i < 8; ++i) {
            const int tb = (blk - 1024) * 8 + i;     // 0..2047
            const int f0 = (tb >> 5) * 32, n0 = (tb & 31) * 32;
            float4 v = *(const float4*)(w + (size_t)(f0 + r) * N_ + n0 + c4);
            __syncthreads();
            t[r][c4 + 0] = v.x; t[r][c4 + 1] = v.y;
            t[r][c4 + 2] = v.z; t[r][c4 + 3] = v.w;
            __syncthreads();
            ushort4 u = make_ushort4(f2bf(t[c4 + 0][r]), f2bf(t[c4 + 1][r]),
                                     f2bf(t[c4 + 2][r]), f2bf(t[c4 + 3][r]));
            *(ushort4*)(wt + (size_t)(n0 + r) * F_ + f0 + c4) = u;
        }
    }
}

// ---- MFMA GEMM with LDS double-buffer (reg-staged, XOR-swizzled) ----
// BM=BN=64, BK=64, 4 waves each 32x32, grid (8,16,KSPLIT)=512 blocks (2/CU).
// Split-K via atomicAdd into memset act (r2-proven epilogue).
__global__ __launch_bounds__(256) void gemm_mfma_kernel(const ushort* __restrict__ xb,
                                                        const ushort* __restrict__ wt,
                                                        float* __restrict__ act) {
    __shared__ ushort As[2][64 * 64];   // [buf][row*64 + chunk*8], chunk XOR-swizzled
    __shared__ ushort Bs[2][64 * 64];

    const int bm0 = blockIdx.x * 64;   // 8
    const int bn0 = blockIdx.y * 64;   // 16
    const int f0  = blockIdx.z * KCH;  // 4
    const int tid = threadIdx.x;
    const int l   = tid & 63;
    const int w   = tid >> 6;
    const int mw  = (w >> 1) * 32;
    const int nw  = (w & 1) * 32;
    const int lr  = l & 15;
    const int lkc = l >> 4;            // 0..3 (k-chunk within 32-k sub)
    const int sw  = lr & 7;            // read-side swizzle (rows mw/nw,+16 are ≡0 mod 8)

    // staging: thread t owns chunks 2t, 2t+1 of each 512-chunk tile (chunk=16B)
    const int r0 = tid >> 2;           // row 0..63 (4 threads/row)
    const int c0 = (tid & 3) * 2;      // even chunk
    const int c1 = c0 + 1;
    const ushort* gA0 = xb + (size_t)(bm0 + r0) * F_ + f0 + c0 * 8;
    const ushort* gA1 = gA0 + 8;
    const ushort* gB0 = wt + (size_t)(bn0 + r0) * F_ + f0 + c0 * 8;
    const ushort* gB1 = gB0 + 8;
    const int wA0 = r0 * 64 + ((c0 ^ (r0 & 7)) * 8);
    const int wA1 = r0 * 64 + ((c1 ^ (r0 & 7)) * 8);

    f32x4 acc00 = {}, acc01 = {}, acc10 = {}, acc11 = {};

    // prologue: stage step 0
    uint4 a0v = *(const uint4*)gA0;
    uint4 a1v = *(const uint4*)gA1;
    uint4 b0v = *(const uint4*)gB0;
    uint4 b1v = *(const uint4*)gB1;
    *(uint4*)&As[0][wA0] = a0v; *(uint4*)&As[0][wA1] = a1v;
    *(uint4*)&Bs[0][wA0] = b0v; *(uint4*)&Bs[0][wA1] = b1v;
    __syncthreads();

    #pragma unroll
    for (int s = 0; s < NSTEP; ++s) {
        const int cur = s & 1, nxt = cur ^ 1;
        if (s < NSTEP - 1) {   // issue next-tile loads (latency hides under MFMA)
            a0v = *(const uint4*)(gA0 + (s + 1) * BK);
            a1v = *(const uint4*)(gA1 + (s + 1) * BK);
            b0v = *(const uint4*)(gB0 + (s + 1) * BK);
            b1v = *(const uint4*)(gB1 + (s + 1) * BK);
        }
        #pragma unroll
        for (int ks = 0; ks < 2; ++ks) {
            const int cb = ks * 4 + lkc;             // chunk 0..7
            short8 a_0 = *(const short8*)&As[cur][(mw + lr) * 64      + ((cb ^ sw) * 8)];
            short8 a_1 = *(const short8*)&As[cur][(mw + 16 + lr) * 64 + ((cb ^ sw) * 8)];
            short8 b_0 = *(const short8*)&Bs[cur][(nw + lr) * 64      + ((cb ^ sw) * 8)];
            short8 b_1 = *(const short8*)&Bs[cur][(nw + 16 + lr) * 64 + ((cb ^ sw) * 8)];
            acc00 = __builtin_amdgcn_mfma_f32_16x16x32_bf16(a_0, b_0, acc00, 0, 0, 0);
            acc01 = __builtin_amdgcn_mfma_f32_16x16x32_bf16(a_0, b_1, acc01, 0, 0, 0);
            acc10 = __builtin_amdgcn_mfma_f32_16x16x32_bf16(a_1, b_0, acc10, 0, 0, 0);
            acc11 = __builtin_amdgcn_mfma_f32_16x16x32_bf16(a_1, b_1, acc11, 0, 0, 0);
        }
        if (s < NSTEP - 1) {   // compiler inserts vmcnt wait before these writes
            *(uint4*)&As[nxt][wA0] = a0v; *(uint4*)&As[nxt][wA1] = a1v;
            *(uint4*)&Bs[nxt][wA0] = b0v; *(uint4*)&Bs[nxt][wA1] = b1v;
        }
        __syncthreads();
    }

    // epilogue: D layout col=l&15 (n), row=(l>>4)*4+reg (m); atomic split-K accumulate
    #pragma unroll
    for (int mi = 0; mi < 2; ++mi) {
        #pragma unroll
        for (int ni = 0; ni < 2; ++ni) {
            const f32x4 a = (mi == 0) ? (ni == 0 ? acc00 : acc01)
                                      : (ni == 0 ? acc10 : acc11);
            const int n = bn0 + nw + ni * 16 + lr;
            const int k = n >> 4, d = n & 15;
            const int mbase = bm0 + mw + mi * 16 + lkc * 4;
            float* dst = act + ((size_t)k * B_ + mbase) * D_ + d;
            #pragma unroll
            for (int r = 0; r < 4; ++r)
                atomicAdd(dst + r * D_, a[r]);
        }
    }
}

// ---- pairwise: f16 LDS, packed-half2 math. 512 thr, 8 waves x 64 b2 ----
__global__ __launch_bounds__(512) void pairwise_kernel(const float* __restrict__ act,
                                                       float* __restrict__ out) {
    __shared__ __half2 s2[B_ * D_ / 2];   // 16 KB
    __shared__ float red[8][64];

    const int bt = blockIdx.x;    // 8
    const int k  = blockIdx.y;    // 64
    const int tid  = threadIdx.x;
    const int lane = tid & 63;
    const int wave = tid >> 6;

    // stage k-slice as f16 (8192 f32 -> 8192 f16)
    const f32x4* src = (const f32x4*)(act + (size_t)k * (B_ * D_));
    #pragma unroll
    for (int i = 0; i < 4; ++i) {
        const int idx = tid + i * 512;
        f32x4 v = src[idx];
        s2[idx * 2]     = __floats2half2_rn(v[0], v[1]);
        s2[idx * 2 + 1] = __floats2half2_rn(v[2], v[3]);
    }
    // own row from GLOBAL (coalesced; avoids strided-LDS conflict), same rounding
    const int b = bt * 64 + lane;
    __half2 ar[8];
    {
        const f32x4* arow = (const f32x4*)(act + ((size_t)k * B_ + b) * D_);
        #pragma unroll
        for (int i = 0; i < 4; ++i) {
            f32x4 v = arow[i];
            ar[i * 2]     = __floats2half2_rn(v[0], v[1]);
            ar[i * 2 + 1] = __floats2half2_rn(v[2], v[3]);
        }
    }
    __syncthreads();

    float p = 0.0f;
    const int b2lo = wave * 64;
    #pragma unroll 4
    for (int b2 = b2lo; b2 < b2lo + 64; ++b2) {
        const __half2* vr = &s2[b2 * 8];   // 32B broadcast: 2x ds_read_b128
        __half2 sA = __habs2(__hsub2(ar[0], vr[0]));
        __half2 sB = __habs2(__hsub2(ar[1], vr[1]));
        sA = __hadd2(sA, __habs2(__hsub2(ar[2], vr[2])));
        sB = __hadd2(sB, __habs2(__hsub2(ar[3], vr[3])));
        sA = __hadd2(sA, __habs2(__hsub2(ar[4], vr[4])));
        sB = __hadd2(sB, __habs2(__hsub2(ar[5], vr[5])));
        sA = __hadd2(sA, __habs2(__hsub2(ar[6], vr[6])));
        sB = __hadd2(sB, __habs2(__hsub2(ar[7], vr[7])));
        sA = __hadd2(sA, sB);
        const float dist = __low2float(sA) + __high2float(sA);
        p += exp2_neg(dist);
    }

    red[wave][lane] = p;
    __syncthreads();
    if (wave == 0) {
        float total = 0.0f;
        #pragma unroll
        for (int i = 0; i < 8; ++i) total += red[i][lane];
        out[(size_t)b * OUTW + F_ + k] = total;
    }
}

extern "C" void kernel_launch(void* const* d_in, const int* in_sizes, int n_in,
                              void* d_out, int out_size, void* d_ws, size_t ws_size,
                              hipStream_t stream) {
    const float* x = (const float*)d_in[0];
    const float* wsrc = (const float*)d_in[1];
    float* out = (float*)d_out;

    // ws: xb bf16 [512][2048] (2MB) | wt bf16 [1024][2048] (4MB) | act f32 [64][512][16] (2MB)
    ushort* xb  = (ushort*)d_ws;
    ushort* wt  = (ushort*)((char*)d_ws + (size_t)2 * 1024 * 1024);
    float*  act = (float*)((char*)d_ws + (size_t)6 * 1024 * 1024);

    hipMemsetAsync(act, 0, (size_t)K_ * B_ * D_ * sizeof(float), stream);
    prep_kernel<<<1280, 256, 0, stream>>>(x, wsrc, out, xb, wt);
    gemm_mfma_kernel<<<dim3(8, 16, KSPLIT), 256, 0, stream>>>(xb, wt, act);
    pairwise_kernel<<<dim3(8, K_), 512, 0, stream>>>(act, out);
}